// Round 4
// baseline (356.787 us; speedup 1.0000x reference)
//
#include <hip/hip_runtime.h>
#include <hip/hip_fp16.h>
#include <math.h>

// B=8, S=1024, D=256, H=8, DH=32
constexpr int Bsz = 8, Ssz = 1024, Dsz = 256, Hn = 8, DHn = 32;
constexpr int SST = 1160;  // attn LDS row stride in shorts

typedef __attribute__((ext_vector_type(8))) short short8;
typedef __attribute__((ext_vector_type(4))) float floatx4;
typedef __attribute__((ext_vector_type(2))) float floatx2;

#define DEV static __device__ __forceinline__

DEV short f2bf(float f) {  // fp32 -> bf16 RNE
  union { float f; unsigned u; } x; x.f = f;
  return (short)((x.u + 0x7fffu + ((x.u >> 16) & 1u)) >> 16);
}
DEV short f2h(float f) {
  __half h = __float2half(f);
  return *(short*)&h;
}
DEV unsigned bfpk(float lo, float hi) {  // v_cvt_pk_bf16_f32: {hi,lo} -> 2xbf16
  unsigned r;
  asm("v_cvt_pk_bf16_f32 %0, %1, %2" : "=v"(r) : "v"(lo), "v"(hi));
  return r;
}
DEV float ex2(float x) {  // raw v_exp_f32 (2^x)
#if __has_builtin(__builtin_amdgcn_exp2f)
  return __builtin_amdgcn_exp2f(x);
#else
  return __expf(x * 0.69314718055994531f);
#endif
}
DEV float wsum(float v) {
#pragma unroll
  for (int off = 32; off > 0; off >>= 1) v += __shfl_xor(v, off, 64);
  return v;
}

// ============ W pre-convert: fp32 row-major -> bf16 MFMA B-frag order =======
// layout: [kblk(8)][ntile(16)][lane(64)][8 bf16]; element =
//   W[ntile*16 + (lane&15)][kblk*32 + (lane>>4)*8 + j]
__global__ __launch_bounds__(256) void cvt_wfrag(const float* __restrict__ Wq,
                                                 const float* __restrict__ Wv,
                                                 const float* __restrict__ Wo,
                                                 short* __restrict__ dst) {
  const int which = blockIdx.y;
  const float* W = (which == 0) ? Wq : (which == 1) ? Wv : Wo;
  const int t = blockIdx.x * 256 + threadIdx.x;  // 0..8191
  const int ln = t & 63, nt = (t >> 6) & 15, kblk = t >> 10;
  const float* src = W + (size_t)(nt * 16 + (ln & 15)) * 256 + kblk * 32 + (ln >> 4) * 8;
  const float4 a = *(const float4*)src;
  const float4 b = *(const float4*)(src + 4);
  const float tmp[8] = {a.x, a.y, a.z, a.w, b.x, b.y, b.z, b.w};
  short8 s;
#pragma unroll
  for (int j = 0; j < 8; ++j) s[j] = f2bf(tmp[j]);
  *(short8*)(dst + ((size_t)which << 16) + (size_t)t * 8) = s;
}

// ============ projections: 32 rows x full N=256 per block ==================
// Xs: 32x80 bf16, granule-XOR swizzled. Wave w owns n-range [w*64, w*64+64).
__global__ __launch_bounds__(256, 4) void proj_qkv2(
    const float* __restrict__ qi, const float* __restrict__ ki, const float* __restrict__ vi,
    const short* __restrict__ Wfrag, const float* __restrict__ bq, const float* __restrict__ bv,
    short* __restrict__ qh, short* __restrict__ kh, short* __restrict__ vt) {
  __shared__ short Xs[32 * 80];
  const int which = blockIdx.y;
  const float* X = (which == 0) ? qi : (which == 1) ? ki : vi;
  const short* Wf = Wfrag + ((which == 2) ? (1 << 16) : 0);
  const float* bias = (which == 2) ? bv : bq;
  const int tid = threadIdx.x, ln = tid & 63, w = tid >> 6;
  const int lm = ln & 15, qq = ln >> 4;
  const int bm = blockIdx.x;  // 256 blocks of 32 rows
  const float* Xb = X + (size_t)bm * 32 * 256;
  floatx4 acc[2][4] = {};

  for (int k0 = 0; k0 < 4; ++k0) {
    __syncthreads();
    {
      const int row = tid >> 3, cg = tid & 7;
#pragma unroll
      for (int i = 0; i < 2; ++i) {
        const float4 f = *(const float4*)(Xb + (size_t)row * 256 + k0 * 64 + cg * 8 + i * 4);
        short4 s; s.x = f2bf(f.x); s.y = f2bf(f.y); s.z = f2bf(f.z); s.w = f2bf(f.w);
        *(short4*)(Xs + row * 80 + (cg ^ (row & 7)) * 8 + i * 4) = s;
      }
    }
    __syncthreads();
#pragma unroll
    for (int ks = 0; ks < 2; ++ks) {
      const int kblk = k0 * 2 + ks;
      short8 a[2], b[4];
#pragma unroll
      for (int mt = 0; mt < 2; ++mt) {
        const int row = mt * 16 + lm;
        a[mt] = *(const short8*)(Xs + row * 80 + (((ks * 4 + qq)) ^ (row & 7)) * 8);
      }
#pragma unroll
      for (int nt = 0; nt < 4; ++nt)
        b[nt] = *(const short8*)(Wf + ((size_t)(kblk * 16 + w * 4 + nt) * 64 + ln) * 8);
#pragma unroll
      for (int mt = 0; mt < 2; ++mt)
#pragma unroll
        for (int nt = 0; nt < 4; ++nt)
          acc[mt][nt] = __builtin_amdgcn_mfma_f32_16x16x32_bf16(a[mt], b[nt], acc[mt][nt], 0, 0, 0);
    }
  }

#pragma unroll
  for (int mt = 0; mt < 2; ++mt) {
#pragma unroll
    for (int nt = 0; nt < 4; ++nt) {
      const int n = w * 64 + nt * 16 + lm;
      const float bval = bias[n];
      const int m0 = bm * 32 + mt * 16 + qq * 4;
      const int h = n >> 5, dh = n & 31;
      if (which <= 1) {  // head-split [B,H,S,DH]
        short* dst = (which == 0) ? qh : kh;
#pragma unroll
        for (int r = 0; r < 4; ++r) {
          const int m = m0 + r, b_ = m >> 10, s = m & 1023;
          dst[(((size_t)(b_ * Hn + h) << 10) + s) * DHn + dh] = f2bf(acc[mt][nt][r] + bval);
        }
      } else {  // V^T [B,H,DH,S]
        const int b_ = m0 >> 10, s0 = m0 & 1023;
        short4 pk;
        pk.x = f2bf(acc[mt][nt][0] + bval);
        pk.y = f2bf(acc[mt][nt][1] + bval);
        pk.z = f2bf(acc[mt][nt][2] + bval);
        pk.w = f2bf(acc[mt][nt][3] + bval);
        *(short4*)(vt + ((size_t)((b_ * Hn + h) * DHn + dh) << 10) + s0) = pk;
      }
    }
  }
}

__global__ __launch_bounds__(256, 4) void proj_out2(
    const short* __restrict__ oc, const short* __restrict__ Wfrag,
    const float* __restrict__ bo, float* __restrict__ out) {
  __shared__ short Xs[32 * 80];
  const short* Wf = Wfrag + (2 << 16);
  const int tid = threadIdx.x, ln = tid & 63, w = tid >> 6;
  const int lm = ln & 15, qq = ln >> 4;
  const int bm = blockIdx.x;
  const short* Xb = oc + (size_t)bm * 32 * 256;
  floatx4 acc[2][4] = {};

  for (int k0 = 0; k0 < 4; ++k0) {
    __syncthreads();
    {
      const int row = tid >> 3, cg = tid & 7;
      const short8 s = *(const short8*)(Xb + (size_t)row * 256 + k0 * 64 + cg * 8);
      *(short8*)(Xs + row * 80 + (cg ^ (row & 7)) * 8) = s;
    }
    __syncthreads();
#pragma unroll
    for (int ks = 0; ks < 2; ++ks) {
      const int kblk = k0 * 2 + ks;
      short8 a[2], b[4];
#pragma unroll
      for (int mt = 0; mt < 2; ++mt) {
        const int row = mt * 16 + lm;
        a[mt] = *(const short8*)(Xs + row * 80 + (((ks * 4 + qq)) ^ (row & 7)) * 8);
      }
#pragma unroll
      for (int nt = 0; nt < 4; ++nt)
        b[nt] = *(const short8*)(Wf + ((size_t)(kblk * 16 + w * 4 + nt) * 64 + ln) * 8);
#pragma unroll
      for (int mt = 0; mt < 2; ++mt)
#pragma unroll
        for (int nt = 0; nt < 4; ++nt)
          acc[mt][nt] = __builtin_amdgcn_mfma_f32_16x16x32_bf16(a[mt], b[nt], acc[mt][nt], 0, 0, 0);
    }
  }
#pragma unroll
  for (int mt = 0; mt < 2; ++mt)
#pragma unroll
    for (int nt = 0; nt < 4; ++nt) {
      const int n = w * 64 + nt * 16 + lm;
      const float bval = bo[n];
      const int m0 = bm * 32 + mt * 16 + qq * 4;
#pragma unroll
      for (int r = 0; r < 4; ++r)
        __builtin_nontemporal_store(acc[mt][nt][r] + bval, out + (size_t)(m0 + r) * 256 + n);
    }
}

// ======================= fused attention ===================================
// phase2 v5: packed-fp32 issue-slot reduction.
//  - pass B + write pass in float2 vectors so the backend forms
//    v_pk_fma_f32 / v_pk_mul_f32 / v_pk_add_f32 (2 elems / instr).
//  - eff = 2^(g*dist) = 2^(-sqrt(g^2*tail*pos)): pos' = g^2*pos kept
//    incrementally, removing the g*dist mul; neg is a free exp2 modifier.
//  - diagonal-chunk mask applied ONCE on sv (-inf); 2^(-inf)=0 flows
//    through both passes, no pass-B cndmask.
template <int NP>
DEV void phase2(short* ss, float* shead, int row0, int w, int ln, float gsq) {
  const int c0 = ln * 4;
  for (int rr = 0; rr < 4; ++rr) {
    const int m = w * 4 + rr;
    const int irow = row0 + m;
    short* srow = ss + m * SST;

    floatx2 sv01[NP], sv23[NP], e01[NP], e23[NP];
    float ls[NP];

    // pass A: load t (= score*log2e) from fp16 LDS; diag-mask sv to -inf;
    // e = 2^t; per-lane chunk sums.
#pragma unroll
    for (int p = 0; p < NP; ++p) {
      const uint2 u = *(const uint2*)(srow + p * 256 + c0);
      const float2 f0 = __half22float2(*(const __half2*)&u.x);
      const float2 f1 = __half22float2(*(const __half2*)&u.y);
      float t0 = f0.x, t1 = f0.y, t2 = f1.x, t3 = f1.y;
      if (p == NP - 1) {  // only diagonal chunk can be masked
        const int cb = p * 256 + c0;
        t0 = (cb + 0 <= irow) ? t0 : -INFINITY;
        t1 = (cb + 1 <= irow) ? t1 : -INFINITY;
        t2 = (cb + 2 <= irow) ? t2 : -INFINITY;
        t3 = (cb + 3 <= irow) ? t3 : -INFINITY;
      }
      sv01[p].x = t0; sv01[p].y = t1; sv23[p].x = t2; sv23[p].y = t3;
      e01[p].x = ex2(t0); e01[p].y = ex2(t1);
      e23[p].x = ex2(t2); e23[p].y = ex2(t3);
      ls[p] = (e01[p].x + e01[p].y) + (e23[p].x + e23[p].y);
    }

    // NP independent wave-scans in lockstep, then serial prefix of totals.
    float incl[NP];
#pragma unroll
    for (int p = 0; p < NP; ++p) incl[p] = ls[p];
#pragma unroll
    for (int off = 1; off < 64; off <<= 1) {
#pragma unroll
      for (int p = 0; p < NP; ++p) {
        const float y = __shfl_up(incl[p], off, 64);
        if (ln >= off) incl[p] += y;
      }
    }
    float excl[NP], Z = 0.f;
#pragma unroll
    for (int p = 0; p < NP; ++p) {
      excl[p] = Z + incl[p] - ls[p];
      Z += __shfl(incl[p], 63, 64);
    }
    const float invZ = 1.f / Z;
    const floatx2 invZ2 = {invZ, invZ};
    const floatx2 one2 = {1.f, 1.f};
    const floatx2 clip2 = {1e-5f, 1e-5f};

    // pass B: distance decay + second (unnormalized) softmax numerator.
    floatx2 ls2v = {0.f, 0.f};
#pragma unroll
    for (int p = 0; p < NP; ++p) {
      float cum = excl[p];
      // pos' = g^2 * (irow - c); vectors for the 4 columns of this lane
      const float P0 = gsq * (float)(irow - (p * 256 + c0));
      const floatx2 pos01 = {P0, P0 - gsq};
      const floatx2 pos23 = {P0 - 2.f * gsq, P0 - 3.f * gsq};

      const float cum0 = cum + e01[p].x;
      const float cum1 = cum0 + e01[p].y;
      const float cum2 = cum1 + e23[p].x;
      const float cum3 = cum2 + e23[p].y;
      const floatx2 c01 = {cum0, cum1}, c23 = {cum2, cum3};

      const floatx2 tail01 = one2 - c01 * invZ2;  // pk_fma
      const floatx2 tail23 = one2 - c23 * invZ2;
      const floatx2 tp01 = tail01 * pos01;        // pk_mul
      const floatx2 tp23 = tail23 * pos23;

      floatx2 eff01, eff23;  // 2^(-sqrt(|tp|)), scalar trans ops
      eff01.x = ex2(-sqrtf(__builtin_fabsf(tp01.x)));
      eff01.y = ex2(-sqrtf(__builtin_fabsf(tp01.y)));
      eff23.x = ex2(-sqrtf(__builtin_fabsf(tp23.x)));
      eff23.y = ex2(-sqrtf(__builtin_fabsf(tp23.y)));
      eff01 = __builtin_elementwise_max(eff01, clip2);  // pk_max
      eff23 = __builtin_elementwise_max(eff23, clip2);

      const floatx2 xa01 = sv01[p] * eff01;  // pk_mul (-inf stays -inf)
      const floatx2 xa23 = sv23[p] * eff23;
      floatx2 x01, x23;
      x01.x = ex2(xa01.x); x01.y = ex2(xa01.y);
      x23.x = ex2(xa23.x); x23.y = ex2(xa23.y);
      ls2v += x01;  // pk_add
      ls2v += x23;
      e01[p] = x01;
      e23[p] = x23;
    }
    const float i2 = 1.f / wsum(ls2v.x + ls2v.y);
    const floatx2 i2v = {i2, i2};

    float* grow = shead + (size_t)irow * Ssz;
#pragma unroll
    for (int p = 0; p < NP; ++p) {
      const floatx2 o01 = e01[p] * i2v;  // pk_mul
      const floatx2 o23 = e23[p] * i2v;
      floatx4 o;
      o.x = o01.x; o.y = o01.y; o.z = o23.x; o.w = o23.y;
      __builtin_nontemporal_store(o, (floatx4*)(grow + p * 256 + c0));
      uint2 pk;
      pk.x = bfpk(o01.x, o01.y);
      pk.y = bfpk(o23.x, o23.y);
      *(uint2*)(srow + p * 256 + c0) = pk;
    }
  }
}

__global__ __launch_bounds__(256, 4) void attn_kernel(
    const short* __restrict__ qh, const short* __restrict__ kh,
    const short* __restrict__ vt, const float* __restrict__ gammas,
    float* __restrict__ scores_out, short* __restrict__ oc) {
  __shared__ short ss[16 * SST];

  const int tid = threadIdx.x, ln = tid & 63, w = tid >> 6;
  const int lm = ln & 15, qq = ln >> 4;
  const int bh = blockIdx.x >> 6;
  const int row0 = (63 - (blockIdx.x & 63)) << 4;  // heavy tiles first
  const int h = bh & 7, b = bh >> 3;
  // scale * log2(e): LDS scores hold t = s*log2e so exps are raw v_exp_f32
  const float scaleL2e = 0.17677669529663687f * 1.4426950408889634f;
  const float g2 = -fabsf(gammas[h]) * 1.4426950408889634f;
  const float gsq = g2 * g2;  // eff = 2^(-sqrt(gsq*tail*pos))

  const short* qhead = qh + (size_t)bh * Ssz * DHn;
  const short* khead = kh + (size_t)bh * Ssz * DHn;
  const short* vhead = vt + (size_t)bh * DHn * Ssz;
  float* shead = scores_out + ((size_t)bh << 20);

  const short8 qa = *(const short8*)(qhead + (row0 + lm) * DHn + qq * 8);

  // phase 1: QK^T -> fp16 t-values in LDS (causal tiles only)
  const int ntile = (row0 >> 4) + 1;
  for (int t = w; t < ntile; t += 4) {
    const int n0 = t * 16;
    const short8 kb = *(const short8*)(khead + (n0 + lm) * DHn + qq * 8);
    floatx4 c = {0.f, 0.f, 0.f, 0.f};
    c = __builtin_amdgcn_mfma_f32_16x16x32_bf16(qa, kb, c, 0, 0, 0);
#pragma unroll
    for (int r = 0; r < 4; ++r)
      ss[(qq * 4 + r) * SST + n0 + lm] = f2h(c[r] * scaleL2e);
  }
  __syncthreads();

  // phase 2
  const int NPc = (row0 >> 8) + 1;
  switch (NPc) {
    case 1: phase2<1>(ss, shead, row0, w, ln, gsq); break;
    case 2: phase2<2>(ss, shead, row0, w, ln, gsq); break;
    case 3: phase2<3>(ss, shead, row0, w, ln, gsq); break;
    default: phase2<4>(ss, shead, row0, w, ln, gsq); break;
  }

  // zero-fill masked tail of scores rows (non-temporal)
  if (NPc < 4) {
    const floatx4 z4 = {0.f, 0.f, 0.f, 0.f};
    for (int r = 0; r < 16; ++r) {
      float* grow = shead + (size_t)(row0 + r) * Ssz + NPc * 256;
      for (int i = tid; i < (4 - NPc) * 64; i += 256)
        __builtin_nontemporal_store(z4, ((floatx4*)grow) + i);
    }
  }
  __syncthreads();

  // phase 3: PV via MFMA, two accumulator sets to halve the dep chain
  floatx4 o0 = {0.f, 0.f, 0.f, 0.f}, o1 = {0.f, 0.f, 0.f, 0.f};
  floatx4 p0 = {0.f, 0.f, 0.f, 0.f}, p1 = {0.f, 0.f, 0.f, 0.f};
  const int nkt = (row0 >> 5) + 1;
  int kt = w;
  for (; kt + 4 < nkt; kt += 8) {
    {
      const int k0 = kt * 32;
      const short8 av = *(const short8*)(ss + lm * SST + k0 + qq * 8);
      const short8 b0 = *(const short8*)(vhead + (lm << 10) + k0 + qq * 8);
      const short8 b1 = *(const short8*)(vhead + ((16 + lm) << 10) + k0 + qq * 8);
      o0 = __builtin_amdgcn_mfma_f32_16x16x32_bf16(av, b0, o0, 0, 0, 0);
      o1 = __builtin_amdgcn_mfma_f32_16x16x32_bf16(av, b1, o1, 0, 0, 0);
    }
    {
      const int k0 = (kt + 4) * 32;
      const short8 av = *(const short8*)(ss + lm * SST + k0 + qq * 8);
      const short8 b0 = *(const short8*)(vhead + (lm << 10) + k0 + qq * 8);
      const short8 b1 = *(const short8*)(vhead + ((16 + lm) << 10) + k0 + qq * 8);
      p0 = __builtin_amdgcn_mfma_f32_16x16x32_bf16(av, b0, p0, 0, 0, 0);
      p1 = __builtin_amdgcn_mfma_f32_16x16x32_bf16(av, b1, p1, 0, 0, 0);
    }
  }
  if (kt < nkt) {
    const int k0 = kt * 32;
    const short8 av = *(const short8*)(ss + lm * SST + k0 + qq * 8);
    const short8 b0 = *(const short8*)(vhead + (lm << 10) + k0 + qq * 8);
    const short8 b1 = *(const short8*)(vhead + ((16 + lm) << 10) + k0 + qq * 8);
    o0 = __builtin_amdgcn_mfma_f32_16x16x32_bf16(av, b0, o0, 0, 0, 0);
    o1 = __builtin_amdgcn_mfma_f32_16x16x32_bf16(av, b1, o1, 0, 0, 0);
  }
  o0 = o0 + p0;
  o1 = o1 + p1;
  __syncthreads();
  float* red = (float*)ss;  // alias, 8 KB
#pragma unroll
  for (int r = 0; r < 4; ++r) {
    red[(w * 16 + qq * 4 + r) * 32 + lm] = o0[r];
    red[(w * 16 + qq * 4 + r) * 32 + 16 + lm] = o1[r];
  }
  __syncthreads();
  {
    const int m = tid >> 4, n = tid & 15;
    float a0 = 0.f, a1 = 0.f;
#pragma unroll
    for (int wv = 0; wv < 4; ++wv) {
      a0 += red[(wv * 16 + m) * 32 + n];
      a1 += red[(wv * 16 + m) * 32 + 16 + n];
    }
    const size_t row = ((size_t)b << 10) + row0 + m;
    oc[row * Dsz + h * DHn + n] = f2bf(a0);
    oc[row * Dsz + h * DHn + 16 + n] = f2bf(a1);
  }
}

// ---------------- launch ---------------------------------------------------
extern "C" void kernel_launch(void* const* d_in, const int* in_sizes, int n_in,
                              void* d_out, int out_size, void* d_ws, size_t ws_size,
                              hipStream_t stream) {
  const float* q  = (const float*)d_in[0];
  const float* k  = (const float*)d_in[1];
  const float* v  = (const float*)d_in[2];
  const float* Wq = (const float*)d_in[4];
  const float* bq = (const float*)d_in[5];
  const float* Wv = (const float*)d_in[6];
  const float* bv = (const float*)d_in[7];
  const float* Wo = (const float*)d_in[8];
  const float* bo = (const float*)d_in[9];
  const float* gm = (const float*)d_in[10];

  float* out    = (float*)d_out;                  // [B,S,D] fp32
  float* scores = out + (size_t)Bsz * Ssz * Dsz;  // [B,H,S,S] fp32

  const size_t Q = (size_t)Bsz * Hn * Ssz * DHn;
  short* qh = (short*)d_ws;        // bf16 [B,H,S,DH]
  short* kh = qh + Q;
  short* vt = kh + Q;              // bf16 [B,H,DH,S]
  short* oc = vt + Q;              // bf16 [B,S,D]
  short* Wf = oc + Q;              // bf16 frag-order weights, 3 x 65536

  const dim3 blk(256);
  hipLaunchKernelGGL(cvt_wfrag, dim3(32, 3), blk, 0, stream, Wq, Wv, Wo, Wf);
  hipLaunchKernelGGL(proj_qkv2, dim3(256, 3), blk, 0, stream,
                     q, k, v, Wf, bq, bv, qh, kh, vt);
  hipLaunchKernelGGL(attn_kernel, dim3(Bsz * Hn * (Ssz / 16)), blk, 0, stream,
                     qh, kh, vt, gm, scores, oc);
  hipLaunchKernelGGL(proj_out2, dim3(256), blk, 0, stream, oc, Wf, bo, out);
}